// Round 9
// baseline (14054.462 us; speedup 1.0000x reference)
//
#include <hip/hip_runtime.h>

#define B_    2
#define NSEQ  4096
#define DM    1024
#define H_    16
#define DH    64
#define MF    266
#define MP    272          // padded feature count (pads are zero)
#define NROWS (B_*NSEQ)    // 8192
#define NHROWS (B_*H_*NSEQ) // 131072
#define RATIO 0.06131393394849658f   // 266^-0.5
#define DNORM 0.3535533905932738f    // 64^-0.25
#define KEPS  1e-4f
#define CEPS  1e-6f

typedef unsigned short u16;
typedef unsigned int   u32;

typedef __bf16 bf16x8 __attribute__((ext_vector_type(8)));
typedef float  f32x4  __attribute__((ext_vector_type(4)));

__device__ __forceinline__ float b2f(u16 u){ u32 x = ((u32)u) << 16; return __builtin_bit_cast(float, x); }
__device__ __forceinline__ u16 f2b(float f){
    u32 x = __builtin_bit_cast(u32, f);
    u32 r = x + 0x7fffu + ((x >> 16) & 1u);
    return (u16)(r >> 16);
}
__device__ __forceinline__ u32 enc_max(float f){ u32 b = __builtin_bit_cast(u32, f); return (b & 0x80000000u) ? ~b : (b | 0x80000000u); }
__device__ __forceinline__ float dec_max(u32 u){ u32 b = (u & 0x80000000u) ? (u & 0x7fffffffu) : ~u; return __builtin_bit_cast(float, b); }

// ---------------------------------------------------------------------------
// Per-input dtype detection (robust to either dtype). flag 1=bf16, 0=fp32.
// ---------------------------------------------------------------------------
__global__ void detect_kernel(const u32* __restrict__ src, int nwords,
                              u32* __restrict__ flag)
{
    __shared__ int cnt[256];
    int t = threadIdx.x; int c = 0;
    for (int i = t; i < nwords; i += 256) {
        u32 w = src[i];
        int ea = (int)((w >> 7)  & 0xFF);
        int eb = (int)((w >> 23) & 0xFF);
        c += (ea >= 112 && ea <= 143) ? 1 : 0;
        c += (eb >= 112 && eb <= 143) ? 1 : 0;
    }
    cnt[t] = c; __syncthreads();
    for (int s = 128; s; s >>= 1) { if (t < s) cnt[t] += cnt[t + s]; __syncthreads(); }
    if (t == 0) *flag = (cnt[0] >= (nwords * 3) / 2) ? 1u : 0u;  // 75% of 2*nwords
}

// ---------------------------------------------------------------------------
// Convert n elements (n % 8 == 0) from src (fp32 or bf16 per its flag) to bf16.
// ---------------------------------------------------------------------------
__global__ __launch_bounds__(256)
void conv_kernel(const void* __restrict__ src, u16* __restrict__ dst, int n,
                 const u32* __restrict__ gflag)
{
    int i = (blockIdx.x * 256 + threadIdx.x) * 8;
    if (i >= n) return;
    if (*gflag) {
        *(uint4*)(dst + i) = *(const uint4*)((const u16*)src + i);
    } else {
        const float* s = (const float*)src + i;
        u16 tmp[8];
        #pragma unroll
        for (int j = 0; j < 8; ++j) tmp[j] = f2b(s[j]);
        *(uint4*)(dst + i) = *(uint4*)tmp;
    }
}

// ---------------------------------------------------------------------------
// GEMM (reference-literal): C[r][c] = sum_k A[r][k] * W[c][k] + bias[c]
// (x @ W.T, W stored [out][in]). 128x128 tile, 4 waves, 16x16x32 bf16 MFMA.
// OUT_BF16: 0 -> fp32 C, 1 -> bf16 C.
// ---------------------------------------------------------------------------
template<int OUT_BF16>
__global__ __launch_bounds__(256)
void gemm_nt(const u16* __restrict__ A, const u16* __restrict__ Bm,
             const u16* __restrict__ bias, void* __restrict__ C)
{
    const int K = DM, Nc = DM;
    __shared__ u16 As[128][40];
    __shared__ u16 Bs[128][40];
    int t = threadIdx.x;
    int wave = t >> 6, lane = t & 63;
    int wm = wave >> 1, wn = wave & 1;
    int quad = lane >> 4, l16 = lane & 15;
    int bm = blockIdx.x * 128, bn = blockIdx.y * 128;
    f32x4 acc[4][4];
    #pragma unroll
    for (int i = 0; i < 4; ++i)
        #pragma unroll
        for (int j = 0; j < 4; ++j) acc[i][j] = (f32x4){0.f,0.f,0.f,0.f};

    for (int k0 = 0; k0 < K; k0 += 32) {
        #pragma unroll
        for (int it = 0; it < 2; ++it) {
            int L = t + it * 256;
            int r = L >> 2, c = (L & 3) * 8;
            *(uint4*)&As[r][c] = *(const uint4*)(A + (size_t)(bm + r) * K + k0 + c);
            *(uint4*)&Bs[r][c] = *(const uint4*)(Bm + (size_t)(bn + r) * K + k0 + c);
        }
        __syncthreads();
        bf16x8 af[4], bfr[4];
        #pragma unroll
        for (int i = 0; i < 4; ++i) {
            af[i]  = *(const bf16x8*)&As[wm*64 + i*16 + l16][quad*8];
            bfr[i] = *(const bf16x8*)&Bs[wn*64 + i*16 + l16][quad*8];
        }
        #pragma unroll
        for (int i = 0; i < 4; ++i)
            #pragma unroll
            for (int j = 0; j < 4; ++j)
                acc[i][j] = __builtin_amdgcn_mfma_f32_16x16x32_bf16(af[i], bfr[j], acc[i][j], 0, 0, 0);
        __syncthreads();
    }
    #pragma unroll
    for (int i = 0; i < 4; ++i) {
        #pragma unroll
        for (int j = 0; j < 4; ++j) {
            int col = bn + wn*64 + j*16 + l16;
            float bv = b2f(bias[col]);
            #pragma unroll
            for (int r = 0; r < 4; ++r) {
                int row = bm + wm*64 + i*16 + quad*4 + r;
                float v = acc[i][j][r] + bv;
                if (OUT_BF16) ((u16*)C)[(size_t)row * Nc + col] = f2b(v);
                else          ((float*)C)[(size_t)row * Nc + col] = v;
            }
        }
    }
}

// ---------------------------------------------------------------------------
// prep2: projC[m][d] = bf16(proj[m][d]) (per-input flag); zero gpart/gmax.
// ---------------------------------------------------------------------------
__global__ __launch_bounds__(256)
void prep2(const void* __restrict__ proj, u16* __restrict__ projC,
           u32* __restrict__ gpart, u32* __restrict__ gmax,
           const u32* __restrict__ gflag)
{
    int i = blockIdx.x * 256 + threadIdx.x;
    if (i < 256) gpart[i] = 0u;
    if (i == 256) *gmax = 0u;
    if (i < MF * DH) {
        projC[i] = (*gflag) ? ((const u16*)proj)[i]
                            : f2b(((const float*)proj)[i]);
    }
}

// ---------------------------------------------------------------------------
// Feature map (per-row block). MODE 0: Q. MODE 1: K global-max. MODE 2: K.
// ---------------------------------------------------------------------------
template<int MODE>
__global__ __launch_bounds__(256)
void feat_simple(const float* __restrict__ X, const u16* __restrict__ projC,
                 u16* __restrict__ OutP, u32* __restrict__ gpart,
                 const u32* __restrict__ gmax)
{
    int rid = blockIdx.x;
    int bh = rid >> 12, n = rid & 4095, b = bh >> 4, h = bh & 15;
    int t = threadIdx.x;
    __shared__ float dnS[64];
    __shared__ float red[256];
    if (t < 64) dnS[t] = X[((size_t)(b * NSEQ + n)) * DM + h * DH + t] * DNORM;
    __syncthreads();
    float diag = 0.f;
    #pragma unroll
    for (int d2 = 0; d2 < 64; ++d2) diag += dnS[d2] * dnS[d2];
    diag *= 0.5f;

    float dd1, dd2 = -3.4e38f;
    {
        const u16* pr = projC + (size_t)t * DH;
        float s = 0.f;
        #pragma unroll
        for (int d2 = 0; d2 < 64; ++d2) s += dnS[d2] * b2f(pr[d2]);
        dd1 = s;
    }
    if (t < MF - 256) {
        const u16* pr = projC + (size_t)(t + 256) * DH;
        float s = 0.f;
        #pragma unroll
        for (int d2 = 0; d2 < 64; ++d2) s += dnS[d2] * b2f(pr[d2]);
        dd2 = s;
    }
    red[t] = fmaxf(dd1, dd2);
    __syncthreads();
    for (int s2 = 128; s2; s2 >>= 1) {
        if (t < s2) red[t] = fmaxf(red[t], red[t + s2]);
        __syncthreads();
    }
    float rmax = red[0];

    if (MODE == 1) {
        if (t == 0) atomicMax(&gpart[blockIdx.x & 255], enc_max(rmax));
        return;
    }
    float stab = (MODE == 0) ? rmax : dec_max(*gmax);
    u16* orow = OutP + (size_t)rid * MP;
    orow[t] = f2b(RATIO * (__expf(dd1 - diag - stab) + KEPS));
    if (t < MF - 256)
        orow[t + 256] = f2b(RATIO * (__expf(dd2 - diag - stab) + KEPS));
    if (t >= MF - 256 && t < MP - 256)
        orow[t + 256] = 0;
}

__global__ void gmax_reduce(const u32* __restrict__ gpart, u32* __restrict__ gmax)
{
    __shared__ u32 r[256];
    int t = threadIdx.x;
    r[t] = gpart[t]; __syncthreads();
    for (int s = 128; s; s >>= 1) { if (t < s) r[t] = max(r[t], r[t + s]); __syncthreads(); }
    if (t == 0) *gmax = r[0];
}

// ---------------------------------------------------------------------------
// Sequential causal scan per (b,h). Wave ml owns m in [ml*68, ml*68+68).
// ---------------------------------------------------------------------------
__global__ __launch_bounds__(256)
void scan_simple(const u16* __restrict__ Qp, const u16* __restrict__ Kp,
                 const u16* __restrict__ Vb, u16* __restrict__ attn)
{
    int bh = blockIdx.x;
    int b = bh >> 4, h = bh & 15;
    int t = threadIdx.x, ml = t >> 6, d = t & 63;
    int m0 = ml * 68;

    float ctx[68], zl[68];
    #pragma unroll
    for (int j = 0; j < 68; ++j) { ctx[j] = 0.f; zl[j] = 0.f; }

    __shared__ u32 qk[272];
    __shared__ u32 vsr[32];
    __shared__ float nps[4][64];
    __shared__ float dps[4];

    for (int n = 0; n < NSEQ; ++n) {
        const u32* qr = (const u32*)(Qp + ((size_t)bh * NSEQ + n) * MP);
        const u32* kr = (const u32*)(Kp + ((size_t)bh * NSEQ + n) * MP);
        const u32* vr = (const u32*)(Vb + ((size_t)(b * NSEQ + n)) * DM + h * DH);
        for (int i = t; i < 304; i += 256) {
            if (i < 136)      qk[i] = qr[i];
            else if (i < 272) qk[i] = kr[i - 136];
            else              vsr[i - 272] = vr[i - 272];
        }
        __syncthreads();
        const u16* qs16 = (const u16*)qk;
        const u16* ks16 = qs16 + 272;
        float vv = b2f(((const u16*)vsr)[d]);
        float np = 0.f, dp = 0.f, sq = 0.f;
        #pragma unroll
        for (int j = 0; j < 68; ++j) {
            int m = m0 + j;
            float kv = b2f(ks16[m]);
            float qv = b2f(qs16[m]);
            ctx[j] += kv * vv;
            zl[j]  += kv;
            np += qv * ctx[j];
            dp += qv * zl[j];
            sq += qv;
        }
        nps[ml][d] = np;
        if (d == 0) dps[ml] = dp + CEPS * sq;
        __syncthreads();
        if (ml == 0) {
            float num = nps[0][d] + nps[1][d] + nps[2][d] + nps[3][d];
            float den = dps[0] + dps[1] + dps[2] + dps[3];
            attn[((size_t)(b * NSEQ + n)) * DM + h * DH + d] = f2b(num / den);
        }
        __syncthreads();
    }
}

// ---------------------------------------------------------------------------
extern "C" void kernel_launch(void* const* d_in, const int* in_sizes, int n_in,
                              void* d_out, int out_size, void* d_ws, size_t ws_size,
                              hipStream_t stream)
{
    (void)n_in; (void)out_size; (void)ws_size;
    // dict order: x, Wq, bq, Wk, bk, Wv, bv, Wo, bo, proj (sizes verified r4/r5)
    const void* x  = d_in[0];
    const void* Wq = d_in[1]; const void* bq = d_in[2];
    const void* Wk = d_in[3]; const void* bk = d_in[4];
    const void* Wv = d_in[5]; const void* bv = d_in[6];
    const void* Wo = d_in[7]; const void* bo = d_in[8];
    const void* proj = d_in[9];

    char* ws = (char*)d_ws;
    size_t off = 0;
    auto alloc = [&](size_t bytes) -> char* {
        char* p = ws + off; off += (bytes + 255) & ~(size_t)255; return p;
    };
    float* QKf  = (float*)alloc((size_t)NROWS * DM * 4);
    u16*   Vb   = (u16*)alloc((size_t)NROWS * DM * 2);
    u16*   Qp   = (u16*)alloc((size_t)NHROWS * MP * 2);
    u16*   Kp   = (u16*)alloc((size_t)NHROWS * MP * 2);
    u16*   projC= (u16*)alloc((size_t)MF * DH * 2);
    u16*   Wb   = (u16*)alloc((size_t)DM * DM * 2);
    u16*   bqb  = (u16*)alloc(DM * 2);
    u16*   bkb  = (u16*)alloc(DM * 2);
    u16*   bvb  = (u16*)alloc(DM * 2);
    u16*   bob  = (u16*)alloc(DM * 2);
    u32*   flags= (u32*)alloc(16 * 4);
    u32*   gmax = (u32*)alloc(256);
    u32*   gpart= (u32*)alloc(256 * 4);
    char*  xatt = alloc((size_t)NROWS * DM * 2);
    u16*   xb   = (u16*)xatt;    // alias: xb dead after gemm K
    u16*   attn = (u16*)xatt;    // scan_simple writes afterwards

    const int nW = DM * DM, nX = NROWS * DM;
    dim3 gg(NROWS / 128, DM / 128);

    for (int i = 0; i < 10; ++i) {
        int n = in_sizes[i];
        int nwords = n / 2; if (nwords > 4096) nwords = 4096;
        detect_kernel<<<1, 256, 0, stream>>>((const u32*)d_in[i], nwords, flags + i);
    }

    prep2<<<(MF * DH + 255) / 256, 256, 0, stream>>>(proj, projC, gpart, gmax, flags + 9);
    conv_kernel<<<(nX + 2047) / 2048, 256, 0, stream>>>(x, xb, nX, flags + 0);
    conv_kernel<<<1, 256, 0, stream>>>(bq, bqb, DM, flags + 2);
    conv_kernel<<<1, 256, 0, stream>>>(bk, bkb, DM, flags + 4);
    conv_kernel<<<1, 256, 0, stream>>>(bv, bvb, DM, flags + 6);
    conv_kernel<<<1, 256, 0, stream>>>(bo, bob, DM, flags + 8);

    conv_kernel<<<(nW + 2047) / 2048, 256, 0, stream>>>(Wv, Wb, nW, flags + 5);
    gemm_nt<1><<<gg, 256, 0, stream>>>(xb, Wb, bvb, Vb);

    conv_kernel<<<(nW + 2047) / 2048, 256, 0, stream>>>(Wq, Wb, nW, flags + 1);
    gemm_nt<0><<<gg, 256, 0, stream>>>(xb, Wb, bqb, QKf);
    feat_simple<0><<<NHROWS, 256, 0, stream>>>(QKf, projC, Qp, gpart, gmax);

    conv_kernel<<<(nW + 2047) / 2048, 256, 0, stream>>>(Wk, Wb, nW, flags + 3);
    gemm_nt<0><<<gg, 256, 0, stream>>>(xb, Wb, bkb, QKf);
    feat_simple<1><<<NHROWS, 256, 0, stream>>>(QKf, projC, Kp, gpart, gmax);
    gmax_reduce<<<1, 256, 0, stream>>>(gpart, gmax);
    feat_simple<2><<<NHROWS, 256, 0, stream>>>(QKf, projC, Kp, gpart, gmax);

    scan_simple<<<32, 256, 0, stream>>>(Qp, Kp, Vb, attn);

    conv_kernel<<<(nW + 2047) / 2048, 256, 0, stream>>>(Wo, Wb, nW, flags + 7);
    // OUTPUT IS FP32 (reference's output dtype, per harness instructions).
    gemm_nt<0><<<gg, 256, 0, stream>>>(attn, Wb, bob, d_out);
}